// Round 10
// baseline (317.490 us; speedup 1.0000x reference)
//
#include <hip/hip_runtime.h>
#include <math.h>

#define TPB 256
#define DEG 10
#define NMON 286   // C(13,3): monomials x^a y^b z^c with a+b+c <= DEG

// Moment factorization: t_ij = u_i . u_j in [-1,1];
//   e^t = sum_k t^k/k!  (deg-10 remainder ~7e-8)
//   Z_i = sum_j e^{t_ij}        = sum_{|a|<=DEG} (M_a / a!) u_i^a
//   S_i = sum_j t_ij e^{t_ij}   = sum_{|a|<=DEG} |a| (M_a / a!) u_i^a
// with moments M_a = sum_j u_j^a. Entropy H_i = ln Z_i - S_i/Z_i - 1e-8*N.
// All kernels enumerate (a,b,c) in the SAME canonical triple-loop order.

// Each thread = one point: accumulate all 286 monomials into global M via
// per-wave shfl reduction + one atomic per monomial per wave.
__global__ __launch_bounds__(TPB) void moments_kernel(const float* __restrict__ vel,
                                                      float* __restrict__ M, int N) {
    int i = blockIdx.x * TPB + threadIdx.x;
    int lane = threadIdx.x & 63;
    float x = 0.f, y = 0.f, z = 0.f, w0 = 0.f;
    if (i < N) {
        x = vel[3 * i]; y = vel[3 * i + 1]; z = vel[3 * i + 2];
        float n = sqrtf(fmaf(x, x, fmaf(y, y, z * z))) + 1e-6f;
        float r = 1.0f / n;
        x *= r; y *= r; z *= r;
        w0 = 1.0f;                 // inactive threads contribute 0 to every monomial
    }
    int idx = 0;
    float xa = w0;
    for (int a = 0; a <= DEG; ++a) {
        float yb = 1.f;
        for (int b = 0; b <= DEG - a; ++b) {
            float zc = 1.f;
            for (int c = 0; c <= DEG - a - b; ++c) {
                float m = xa * yb * zc;
                m += __shfl_down(m, 32);
                m += __shfl_down(m, 16);
                m += __shfl_down(m, 8);
                m += __shfl_down(m, 4);
                m += __shfl_down(m, 2);
                m += __shfl_down(m, 1);
                if (lane == 0) atomicAdd(&M[idx], m);
                ++idx;
                zc *= z;
            }
            yb *= y;
        }
        xa *= x;
    }
}

// Fold 1/(a! b! c!) into the moments; CT[idx] = {A, |alpha|*A}. Also zero out[0]
// (runs before rows_kernel on the stream).
__global__ __launch_bounds__(512) void coeffs_kernel(const float* __restrict__ M,
                                                     float2* __restrict__ CT,
                                                     float* __restrict__ out) {
    int tid = threadIdx.x;
    if (tid == NMON) out[0] = 0.0f;
    if (tid < NMON) {
        int aa = 0, bb = 0, cc = 0, k = 0;
        for (int a = 0; a <= DEG; ++a)
            for (int b = 0; b <= DEG - a; ++b)
                for (int c = 0; c <= DEG - a - b; ++c) {
                    if (k == tid) { aa = a; bb = b; cc = c; }
                    ++k;
                }
        float f = 1.f;
        for (int q = 2; q <= aa; ++q) f *= (float)q;
        for (int q = 2; q <= bb; ++q) f *= (float)q;
        for (int q = 2; q <= cc; ++q) f *= (float)q;   // <= 10! = 3628800, fp32-exact
        float A = M[tid] / f;
        CT[tid] = make_float2(A, (float)(aa + bb + cc) * A);
    }
}

// Each thread = one row: evaluate Z, S against the LDS-cached table, compute
// entropy, block-reduce the mean into out[0].
__global__ __launch_bounds__(TPB) void rows_kernel(const float* __restrict__ vel,
                                                   const float2* __restrict__ CT,
                                                   float* __restrict__ out, int N) {
    __shared__ float2 ct[NMON];
    int tid = threadIdx.x;
    for (int k = tid; k < NMON; k += TPB) ct[k] = CT[k];
    __syncthreads();

    int i = blockIdx.x * TPB + tid;
    float contrib = 0.0f;
    if (i < N) {
        float x = vel[3 * i], y = vel[3 * i + 1], z = vel[3 * i + 2];
        float n = sqrtf(fmaf(x, x, fmaf(y, y, z * z))) + 1e-6f;
        float r = 1.0f / n;
        x *= r; y *= r; z *= r;

        float Z = 0.f, S = 0.f;
        int idx = 0;
        float xa = 1.f;
        for (int a = 0; a <= DEG; ++a) {
            float yb = 1.f;
            for (int b = 0; b <= DEG - a; ++b) {
                float zc = 1.f;
                for (int c = 0; c <= DEG - a - b; ++c) {
                    float m = xa * yb * zc;
                    float2 cc2 = ct[idx];
                    Z = fmaf(m, cc2.x, Z);
                    S = fmaf(m, cc2.y, S);
                    ++idx;
                    zc *= z;
                }
                yb *= y;
            }
            xa *= x;
        }
        float H = logf(Z) - S / Z - 1e-8f * (float)N;
        contrib = H / (float)N;
    }
    for (int off = 32; off; off >>= 1) contrib += __shfl_down(contrib, off);
    __shared__ float red[TPB / 64];
    if ((threadIdx.x & 63) == 0) red[threadIdx.x >> 6] = contrib;
    __syncthreads();
    if (threadIdx.x == 0) {
        float s = 0.f;
        for (int w = 0; w < TPB / 64; ++w) s += red[w];
        atomicAdd(out, s);
    }
}

extern "C" void kernel_launch(void* const* d_in, const int* in_sizes, int n_in,
                              void* d_out, int out_size, void* d_ws, size_t ws_size,
                              hipStream_t stream) {
    const float* vel = (const float*)d_in[0];
    // d_in[1] (positions) is unused by the reference math.
    int N = in_sizes[0] / 3;
    float* out = (float*)d_out;

    float* M = (float*)d_ws;                                   // NMON floats
    float2* CT = (float2*)((char*)d_ws + ((NMON * 4 + 15) / 16) * 16);  // NMON float2

    int nb = (N + TPB - 1) / TPB;
    hipMemsetAsync(M, 0, NMON * sizeof(float), stream);
    moments_kernel<<<nb, TPB, 0, stream>>>(vel, M, N);
    coeffs_kernel<<<1, 512, 0, stream>>>(M, CT, out);
    rows_kernel<<<nb, TPB, 0, stream>>>(vel, CT, out, N);
}

// Round 11
// 86.363 us; speedup vs baseline: 3.6762x; 3.6762x over previous
//
#include <hip/hip_runtime.h>
#include <math.h>

#define TPB 256
#define DEG 10
#define NMON 286   // C(13,3): monomials x^a y^b z^c with a+b+c <= DEG

// Moment factorization: t_ij = u_i . u_j in [-1,1];
//   e^t = sum_k t^k/k!  (deg-10 remainder ~7e-8)
//   Z_i = sum_j e^{t_ij}      = sum_{|a|<=DEG} (M_a / a!) u_i^a
//   S_i = sum_j t_ij e^{t_ij} = sum_{|a|<=DEG} |a| (M_a / a!) u_i^a
// with moments M_a = sum_j u_j^a. Entropy H_i = ln Z_i - S_i/Z_i - 1e-8*N.
// Both kernels enumerate (a,b,c) in the SAME canonical triple-loop order.

// One block PER MONOMIAL (286 blocks): threads grid-stride the points,
// branch-free pow via squaring chain + uniform-exponent selects, one block
// reduction, one pure store of CT[mon] = {M/a!, |alpha|*M/a!}. No atomics.
// (R10's point-major version: 64 blocks, serial shfl chain + global atomics
// per monomial -> 250 us at 0.7% VALUBusy. This shape: ~1k independent VALU
// ops per thread, reduction once per block.)
__global__ __launch_bounds__(TPB) void moments_ct_kernel(const float* __restrict__ vel,
                                                         float2* __restrict__ CT,
                                                         float* __restrict__ out, int N) {
    int mon = blockIdx.x;
    if (mon == 0 && threadIdx.x == 0) out[0] = 0.0f;  // stream-ordered before rows

    // decode mon -> (aa, bb, cc) in canonical order (scalar, ~286 cheap iters)
    int aa = 0, bb = 0, cc = 0;
    {
        int k = 0;
        for (int a = 0; a <= DEG; ++a)
            for (int b = 0; b <= DEG - a; ++b)
                for (int c = 0; c <= DEG - a - b; ++c) {
                    if (k == mon) { aa = a; bb = b; cc = c; }
                    ++k;
                }
    }

    float acc = 0.0f;
    for (int j = threadIdx.x; j < N; j += TPB) {
        float x = vel[3 * j], y = vel[3 * j + 1], z = vel[3 * j + 2];
        float n = sqrtf(fmaf(x, x, fmaf(y, y, z * z))) + 1e-6f;
        float r = 1.0f / n;
        x *= r; y *= r; z *= r;
        // x^aa * y^bb * z^cc, exponents block-uniform, branch-free selects
        float x2 = x * x, x4 = x2 * x2, x8 = x4 * x4;
        float y2 = y * y, y4 = y2 * y2, y8 = y4 * y4;
        float z2 = z * z, z4 = z2 * z2, z8 = z4 * z4;
        float m = 1.0f;
        m *= (aa & 1) ? x : 1.0f;  m *= (aa & 2) ? x2 : 1.0f;
        m *= (aa & 4) ? x4 : 1.0f; m *= (aa & 8) ? x8 : 1.0f;
        m *= (bb & 1) ? y : 1.0f;  m *= (bb & 2) ? y2 : 1.0f;
        m *= (bb & 4) ? y4 : 1.0f; m *= (bb & 8) ? y8 : 1.0f;
        m *= (cc & 1) ? z : 1.0f;  m *= (cc & 2) ? z2 : 1.0f;
        m *= (cc & 4) ? z4 : 1.0f; m *= (cc & 8) ? z8 : 1.0f;
        acc += m;
    }

    // block reduce (wave shfl + LDS across 4 waves)
    for (int off = 32; off; off >>= 1) acc += __shfl_down(acc, off);
    __shared__ float red[TPB / 64];
    if ((threadIdx.x & 63) == 0) red[threadIdx.x >> 6] = acc;
    __syncthreads();
    if (threadIdx.x == 0) {
        float Msum = 0.0f;
        for (int w = 0; w < TPB / 64; ++w) Msum += red[w];
        float f = 1.0f;
        for (int q = 2; q <= aa; ++q) f *= (float)q;
        for (int q = 2; q <= bb; ++q) f *= (float)q;
        for (int q = 2; q <= cc; ++q) f *= (float)q;  // <= 10! = 3628800, fp32-exact
        float A = Msum / f;
        CT[mon] = make_float2(A, (float)(aa + bb + cc) * A);
    }
}

// Each thread = one row: evaluate Z, S against the LDS-cached table, compute
// entropy, block-reduce the mean into out[0].
__global__ __launch_bounds__(TPB) void rows_kernel(const float* __restrict__ vel,
                                                   const float2* __restrict__ CT,
                                                   float* __restrict__ out, int N) {
    __shared__ float2 ct[NMON];
    int tid = threadIdx.x;
    for (int k = tid; k < NMON; k += TPB) ct[k] = CT[k];
    __syncthreads();

    int i = blockIdx.x * TPB + tid;
    float contrib = 0.0f;
    if (i < N) {
        float x = vel[3 * i], y = vel[3 * i + 1], z = vel[3 * i + 2];
        float n = sqrtf(fmaf(x, x, fmaf(y, y, z * z))) + 1e-6f;
        float r = 1.0f / n;
        x *= r; y *= r; z *= r;

        float Z = 0.f, S = 0.f;
        int idx = 0;
        float xa = 1.f;
        for (int a = 0; a <= DEG; ++a) {
            float yb = 1.f;
            for (int b = 0; b <= DEG - a; ++b) {
                float zc = 1.f;
                for (int c = 0; c <= DEG - a - b; ++c) {
                    float m = xa * yb * zc;
                    float2 cc2 = ct[idx];
                    Z = fmaf(m, cc2.x, Z);
                    S = fmaf(m, cc2.y, S);
                    ++idx;
                    zc *= z;
                }
                yb *= y;
            }
            xa *= x;
        }
        float H = logf(Z) - S / Z - 1e-8f * (float)N;
        contrib = H / (float)N;
    }
    for (int off = 32; off; off >>= 1) contrib += __shfl_down(contrib, off);
    __shared__ float red[TPB / 64];
    if ((threadIdx.x & 63) == 0) red[threadIdx.x >> 6] = contrib;
    __syncthreads();
    if (threadIdx.x == 0) {
        float s = 0.f;
        for (int w = 0; w < TPB / 64; ++w) s += red[w];
        atomicAdd(out, s);
    }
}

extern "C" void kernel_launch(void* const* d_in, const int* in_sizes, int n_in,
                              void* d_out, int out_size, void* d_ws, size_t ws_size,
                              hipStream_t stream) {
    const float* vel = (const float*)d_in[0];
    // d_in[1] (positions) is unused by the reference math.
    int N = in_sizes[0] / 3;
    float* out = (float*)d_out;

    float2* CT = (float2*)d_ws;   // NMON float2 (pure stores each call)

    moments_ct_kernel<<<NMON, TPB, 0, stream>>>(vel, CT, out, N);
    rows_kernel<<<(N + TPB - 1) / TPB, TPB, 0, stream>>>(vel, CT, out, N);
}

// Round 12
// 68.571 us; speedup vs baseline: 4.6301x; 1.2595x over previous
//
#include <hip/hip_runtime.h>
#include <math.h>

#define TPB 256
#define DEG 10
#define NMON 286    // C(13,3): monomials x^a y^b z^c with a+b+c <= DEG
#define PCH 16      // point-chunks per monomial: grid = NMON x PCH = 4576 blocks

// Moment factorization: t_ij = u_i . u_j in [-1,1];
//   e^t = sum_k t^k/k!  (deg-10 remainder ~7e-8)
//   Z_i = sum_j e^{t_ij}      = sum_{|a|<=DEG} (M_a / a!) u_i^a
//   S_i = sum_j t_ij e^{t_ij} = sum_{|a|<=DEG} |a| (M_a / a!) u_i^a
// with M_a = sum_j u_j^a. Entropy H_i = ln Z_i - S_i/Z_i - 1e-8*N.
// CT[mon] = M_mon / (a! b! c!); rows folds the |alpha| factor itself.

// Normalize once into U (float4), zero CT and out.
__global__ __launch_bounds__(TPB) void prep_kernel(const float* __restrict__ vel,
                                                   float4* __restrict__ U,
                                                   float* __restrict__ CT,
                                                   float* __restrict__ out, int N) {
    int i = blockIdx.x * TPB + threadIdx.x;
    if (i < NMON) CT[i] = 0.0f;
    if (i == NMON) out[0] = 0.0f;
    if (i < N) {
        float x = vel[3 * i], y = vel[3 * i + 1], z = vel[3 * i + 2];
        float n = sqrtf(fmaf(x, x, fmaf(y, y, z * z))) + 1e-6f;
        float r = 1.0f / n;
        U[i] = make_float4(x * r, y * r, z * r, 0.0f);
    }
}

// grid (NMON, PCH): each block reduces one 1024-point chunk of one monomial.
// Branch-free pow via squaring chain + block-uniform exponent selects.
// One float atomicAdd of partial/a! per block (16 per monomial address).
__global__ __launch_bounds__(TPB) void moments_kernel(const float4* __restrict__ U,
                                                      float* __restrict__ CT, int N) {
    int mon = blockIdx.x;
    // closed-form-ish decode mon -> (aa,bb,cc), canonical (a outer, c inner) order
    int rem = mon, aa = 0, bb = 0;
    for (;; ++aa) {
        int R = DEG - aa, cnt = (R + 1) * (R + 2) / 2;
        if (rem < cnt) break;
        rem -= cnt;
    }
    for (;; ++bb) {
        int cnt = DEG - aa - bb + 1;
        if (rem < cnt) break;
        rem -= cnt;
    }
    int cc = rem;

    int base = blockIdx.y * (N / PCH);
    float acc = 0.0f;
#pragma unroll
    for (int q = 0; q < (N / PCH) / TPB; ++q) {
        int j = base + q * TPB + threadIdx.x;
        float4 u = U[j];
        float x = u.x, y = u.y, z = u.z;
        float x2 = x * x, x4 = x2 * x2, x8 = x4 * x4;
        float y2 = y * y, y4 = y2 * y2, y8 = y4 * y4;
        float z2 = z * z, z4 = z2 * z2, z8 = z4 * z4;
        float m = 1.0f;
        m *= (aa & 1) ? x : 1.0f;  m *= (aa & 2) ? x2 : 1.0f;
        m *= (aa & 4) ? x4 : 1.0f; m *= (aa & 8) ? x8 : 1.0f;
        m *= (bb & 1) ? y : 1.0f;  m *= (bb & 2) ? y2 : 1.0f;
        m *= (bb & 4) ? y4 : 1.0f; m *= (bb & 8) ? y8 : 1.0f;
        m *= (cc & 1) ? z : 1.0f;  m *= (cc & 2) ? z2 : 1.0f;
        m *= (cc & 4) ? z4 : 1.0f; m *= (cc & 8) ? z8 : 1.0f;
        acc += m;
    }

    for (int off = 32; off; off >>= 1) acc += __shfl_down(acc, off);
    __shared__ float red[TPB / 64];
    if ((threadIdx.x & 63) == 0) red[threadIdx.x >> 6] = acc;
    __syncthreads();
    if (threadIdx.x == 0) {
        float Msum = 0.0f;
        for (int w = 0; w < TPB / 64; ++w) Msum += red[w];
        float f = 1.0f;
        for (int q = 2; q <= aa; ++q) f *= (float)q;
        for (int q = 2; q <= bb; ++q) f *= (float)q;
        for (int q = 2; q <= cc; ++q) f *= (float)q;  // <= 10! = 3628800, fp32-exact
        atomicAdd(&CT[mon], Msum / f);
    }
}

// Each thread = one row: evaluate Z, S against the LDS-cached CT (folding the
// |alpha| factor from loop vars), compute entropy, block-reduce mean into out.
__global__ __launch_bounds__(TPB) void rows_kernel(const float4* __restrict__ U,
                                                   const float* __restrict__ CT,
                                                   float* __restrict__ out, int N) {
    __shared__ float ct[NMON];
    int tid = threadIdx.x;
    for (int k = tid; k < NMON; k += TPB) ct[k] = CT[k];
    __syncthreads();

    int i = blockIdx.x * TPB + tid;
    float contrib = 0.0f;
    if (i < N) {
        float4 u = U[i];
        float x = u.x, y = u.y, z = u.z;

        float Z = 0.f, S = 0.f;
        int idx = 0;
        float xa = 1.f;
        for (int a = 0; a <= DEG; ++a) {
            float yb = 1.f;
            for (int b = 0; b <= DEG - a; ++b) {
                float xy = xa * yb;
                float abf = (float)(a + b);
                float zc = 1.f, cf = 0.f;
                for (int c = 0; c <= DEG - a - b; ++c) {
                    float p = xy * zc * ct[idx];
                    Z += p;
                    S = fmaf(abf + cf, p, S);   // |alpha| * p
                    zc *= z;
                    cf += 1.0f;
                    ++idx;
                }
                yb *= y;
            }
            xa *= x;
        }
        float H = logf(Z) - S / Z - 1e-8f * (float)N;
        contrib = H / (float)N;
    }
    for (int off = 32; off; off >>= 1) contrib += __shfl_down(contrib, off);
    __shared__ float red[TPB / 64];
    if ((threadIdx.x & 63) == 0) red[threadIdx.x >> 6] = contrib;
    __syncthreads();
    if (threadIdx.x == 0) {
        float s = 0.f;
        for (int w = 0; w < TPB / 64; ++w) s += red[w];
        atomicAdd(out, s);
    }
}

extern "C" void kernel_launch(void* const* d_in, const int* in_sizes, int n_in,
                              void* d_out, int out_size, void* d_ws, size_t ws_size,
                              hipStream_t stream) {
    const float* vel = (const float*)d_in[0];
    // d_in[1] (positions) is unused by the reference math.
    int N = in_sizes[0] / 3;
    float* out = (float*)d_out;

    char* ws = (char*)d_ws;
    float4* U = (float4*)ws;                                  // N * 16 B
    float* CT = (float*)(ws + (size_t)N * sizeof(float4));    // NMON floats

    int nb = (N + TPB - 1) / TPB;
    prep_kernel<<<nb, TPB, 0, stream>>>(vel, U, CT, out, N);
    dim3 mg(NMON, PCH);
    moments_kernel<<<mg, TPB, 0, stream>>>(U, CT, N);
    rows_kernel<<<nb, TPB, 0, stream>>>(U, CT, out, N);
}